// Round 2
// baseline (16258.231 us; speedup 1.0000x reference)
//
#include <hip/hip_runtime.h>
#include <cstdint>
#include <cstddef>

#define B_SZ 128
#define T_SZ 256
#define V_SZ 1000
#define H_SZ 512
#define NG   2048   // 4*H
#define VP   1024   // padded V

typedef unsigned long long u64;

__device__ __forceinline__ unsigned fkey(float f) {
  unsigned u = __float_as_uint(f);
  return (u & 0x80000000u) ? ~u : (u | 0x80000000u);
}
__device__ __forceinline__ float sigf(float x) { return 1.0f / (1.0f + expf(-x)); }

// agent-scope sense-free grid barrier: bar[0]=count, bar[32]=generation (separate lines)
__device__ __forceinline__ void grid_barrier(unsigned* bar) {
  __syncthreads();
  if (threadIdx.x == 0) {
    __threadfence();  // release all this block's prior writes device-wide
    unsigned g = __hip_atomic_load(bar + 32, __ATOMIC_RELAXED, __HIP_MEMORY_SCOPE_AGENT);
    unsigned a = __hip_atomic_fetch_add(bar, 1u, __ATOMIC_ACQ_REL, __HIP_MEMORY_SCOPE_AGENT);
    if (a == 255u) {
      __hip_atomic_store(bar, 0u, __ATOMIC_RELAXED, __HIP_MEMORY_SCOPE_AGENT);
      __hip_atomic_fetch_add(bar + 32, 1u, __ATOMIC_RELEASE, __HIP_MEMORY_SCOPE_AGENT);
    } else {
      while (__hip_atomic_load(bar + 32, __ATOMIC_RELAXED, __HIP_MEMORY_SCOPE_AGENT) == g)
        __builtin_amdgcn_s_sleep(1);
    }
    __threadfence();  // acquire: invalidate stale L1/L2 before post-barrier reads
  }
  __syncthreads();
}

// ---------------- one-time kernels ----------------

// dst[k][n] = (n < n_valid) ? src[n*srcLD + col_off + k] : 0
__global__ void k_transpose(const float* __restrict__ src, int srcLD, int col_off,
                            float* __restrict__ dst, int dstLD, int n_valid) {
  __shared__ float tile[32][33];
  const int tid = threadIdx.x;
  const int k0 = blockIdx.y * 32, n0 = blockIdx.x * 32;
  const int nl = tid >> 3, kq = (tid & 7) * 4;
  float4 v = make_float4(0.f, 0.f, 0.f, 0.f);
  if (n0 + nl < n_valid)
    v = *(const float4*)(src + (size_t)(n0 + nl) * srcLD + col_off + k0 + kq);
  tile[nl][kq + 0] = v.x; tile[nl][kq + 1] = v.y;
  tile[nl][kq + 2] = v.z; tile[nl][kq + 3] = v.w;
  __syncthreads();
  const int kl = tid >> 3, nq = (tid & 7) * 4;
  float4 o;
  o.x = tile[nq + 0][kl]; o.y = tile[nq + 1][kl];
  o.z = tile[nq + 2][kl]; o.w = tile[nq + 3][kl];
  *(float4*)(dst + (size_t)(k0 + kl) * dstLD + n0 + nq) = o;
}

// base[m][n] = sum_k ctx[m][k] * Wtc[k][n] + b_ih[n] + b_hh[n]
__global__ void k_base(const float* __restrict__ ctx, const float* __restrict__ Wtc,
                       const float* __restrict__ b_ih, const float* __restrict__ b_hh,
                       float* __restrict__ base) {
  const int tid = threadIdx.x;
  const int n0 = blockIdx.x * 32, m0 = blockIdx.y * 32;
  const int ml = tid >> 3, ng = (tid & 7) * 4;
  const float* a = ctx + (size_t)(m0 + ml) * H_SZ;
  const float* b = Wtc + n0 + ng;
  float acc0 = 0.f, acc1 = 0.f, acc2 = 0.f, acc3 = 0.f;
#pragma unroll 4
  for (int k = 0; k < H_SZ; ++k) {
    float av = a[k];
    float4 bv = *(const float4*)(b + (size_t)k * NG);
    acc0 = fmaf(av, bv.x, acc0); acc1 = fmaf(av, bv.y, acc1);
    acc2 = fmaf(av, bv.z, acc2); acc3 = fmaf(av, bv.w, acc3);
  }
  const int n = n0 + ng;
  float* o = base + (size_t)(m0 + ml) * NG + n;
  o[0] = acc0 + b_ih[n + 0] + b_hh[n + 0];
  o[1] = acc1 + b_ih[n + 1] + b_hh[n + 1];
  o[2] = acc2 + b_ih[n + 2] + b_hh[n + 2];
  o[3] = acc3 + b_ih[n + 3] + b_hh[n + 3];
}

__global__ void k_init(const float* __restrict__ ctx, const float* __restrict__ b_out,
                       float* __restrict__ h0, float* __restrict__ bo,
                       unsigned* __restrict__ bar) {
  const int i = blockIdx.x * 256 + threadIdx.x;   // 65536 total
  h0[i] = ctx[i];
  if (i < VP) bo[i] = (i < V_SZ) ? b_out[i] : 0.f;
  if (i < 64) bar[i] = 0u;
}

// ---------------- persistent cooperative kernel ----------------
// 256 blocks x 512 threads. Per step:
//   phase A: gates GEMM (32m x 8q x 4gates, K=1024, 8-wave K-split) + fused LSTM cell
//            c kept in registers (block owns its (m,q) slice for all 256 steps)
//   barrier
//   phase B: logits GEMM (16m x 32v, K=512, 8-wave K-split) + out write + argmax partials
//   barrier
__global__ __launch_bounds__(512, 2) void k_persist(
    const float* __restrict__ Wt, const float* __restrict__ WoT,
    const float* __restrict__ base, const float* __restrict__ etbl,
    const float* __restrict__ coin, const int* __restrict__ tgt,
    const float* __restrict__ bo, float* __restrict__ h0buf, float* __restrict__ h1buf,
    float* __restrict__ out, u64* __restrict__ pk, unsigned* __restrict__ bar) {
  __shared__ float smem[9216];
  __shared__ int idx_s[32];
  const int tid = threadIdx.x;
  const int bid = blockIdx.x;
  const int xcd = bid & 7, slot = bid >> 3;

  // phase A tiling: qtiles grouped per XCD for W L2-residency (1MB/XCD)
  const int qt = xcd * 8 + (slot >> 2);     // 0..63
  const int mtA = slot & 3;                 // 0..3
  const int q0 = qt * 8, m0A = mtA * 32;
  // phase B tiling: vtiles grouped per XCD (WoT slice 256KB/XCD)
  const int vt = xcd * 4 + (slot & 3);      // 0..31
  const int mtB = slot >> 2;                // 0..7
  const int n0B = vt * 32, m0B = mtB * 16;

  const int w = tid >> 6, lane = tid & 63;
  const int rg = lane >> 3, cg = lane & 7;
  // phase A per-lane constants
  float* As = smem + w * 1152;              // [16k][32m] pad36
  float* Bs = As + 576;                     // [16k][32j] pad36
  const int kbA = w * 128;
  const int amA = lane >> 2, afA = (lane & 3) * 4;
  const int bkA = lane >> 3;
  const int bnA = (lane & 7) * 4;
  const int colA = (bnA >> 3) * 512 + q0 + (bnA & 7);  // global W column for local j=bnA
  // phase B per-lane constants
  float* As2 = smem + w * 896;              // [16k][16m] pad20
  float* Bs2 = As2 + 320;                   // [16k][32n] pad36
  const int kbB = w * 64;
  const int amB = lane >> 2;

  // cell-thread constants + preloaded base (loop-invariant)
  const int mlc = tid >> 3, qlc = tid & 7;
  float bsr[4];
  size_t hIdx = 0;
  if (tid < 256) {
#pragma unroll
    for (int g = 0; g < 4; ++g)
      bsr[g] = base[(size_t)(m0A + mlc) * NG + g * 512 + q0 + qlc];
    hIdx = (size_t)(m0A + mlc) * H_SZ + q0 + qlc;
  }
  float creg = 0.f;  // persistent cell state for this thread's (m,q)

  // phase B epilogue constants
  const int mlb = tid >> 5, nlb = tid & 31;
  const int ngB = n0B + nlb, mgB = m0B + mlb;
  const float bor = bo[ngB];
  const size_t outBase = (size_t)mgB * ((size_t)T_SZ * V_SZ) + ngB;

#pragma unroll 1
  for (int t = 0; t < T_SZ; ++t) {
    const float* hRead  = (t & 1) ? h1buf : h0buf;
    float*       hWrite = (t & 1) ? h0buf : h1buf;

    // ---------------- phase A: gates + cell ----------------
    if (tid < 32) {
      int id = 0;
      if (t > 0) {
        if (coin[t] > 0.5f) {
          id = tgt[(m0A + tid) * T_SZ + (t - 1)];
        } else {
          const u64* p = pk + (size_t)(m0A + tid) * 32;
          u64 best = 0ull;
#pragma unroll
          for (int q = 0; q < 32; ++q) { u64 v = p[q]; best = (v > best) ? v : best; }
          id = (int)(~(unsigned)best);
        }
      }
      idx_s[tid] = id;
    }
    __syncthreads();

    {
      float acc[4][4];
#pragma unroll
      for (int i = 0; i < 4; ++i)
#pragma unroll
        for (int j = 0; j < 4; ++j) acc[i][j] = 0.f;

      float4 ra[2], rb[2];
      auto loadA = [&](int s, float4* r) {
        const int k = kbA + s * 16 + afA;
#pragma unroll
        for (int i = 0; i < 2; ++i) {
          const int m_ = amA + i * 16;
          const float* p = (k < 512)
              ? (etbl + (size_t)idx_s[m_] * 512 + k)
              : (hRead + (size_t)(m0A + m_) * H_SZ + (k - 512));
          r[i] = *(const float4*)p;
        }
      };
      auto loadB = [&](int s, float4* r) {
#pragma unroll
        for (int i = 0; i < 2; ++i)
          r[i] = *(const float4*)(Wt + (size_t)(kbA + s * 16 + bkA + i * 8) * NG + colA);
      };

      loadA(0, ra); loadB(0, rb);
#pragma unroll 1
      for (int s = 0; s < 8; ++s) {
#pragma unroll
        for (int i = 0; i < 2; ++i) {
          const int m_ = amA + i * 16;
          As[(afA + 0) * 36 + m_] = ra[i].x;
          As[(afA + 1) * 36 + m_] = ra[i].y;
          As[(afA + 2) * 36 + m_] = ra[i].z;
          As[(afA + 3) * 36 + m_] = ra[i].w;
          *(float4*)(Bs + (bkA + i * 8) * 36 + bnA) = rb[i];
        }
        float4 na[2], nb[2];
        if (s < 7) { loadA(s + 1, na); loadB(s + 1, nb); }
#pragma unroll
        for (int k = 0; k < 16; ++k) {
          float4 a = *(const float4*)(As + k * 36 + rg * 4);
          float4 b = *(const float4*)(Bs + k * 36 + cg * 4);
          acc[0][0] = fmaf(a.x, b.x, acc[0][0]); acc[0][1] = fmaf(a.x, b.y, acc[0][1]);
          acc[0][2] = fmaf(a.x, b.z, acc[0][2]); acc[0][3] = fmaf(a.x, b.w, acc[0][3]);
          acc[1][0] = fmaf(a.y, b.x, acc[1][0]); acc[1][1] = fmaf(a.y, b.y, acc[1][1]);
          acc[1][2] = fmaf(a.y, b.z, acc[1][2]); acc[1][3] = fmaf(a.y, b.w, acc[1][3]);
          acc[2][0] = fmaf(a.z, b.x, acc[2][0]); acc[2][1] = fmaf(a.z, b.y, acc[2][1]);
          acc[2][2] = fmaf(a.z, b.z, acc[2][2]); acc[2][3] = fmaf(a.z, b.w, acc[2][3]);
          acc[3][0] = fmaf(a.w, b.x, acc[3][0]); acc[3][1] = fmaf(a.w, b.y, acc[3][1]);
          acc[3][2] = fmaf(a.w, b.z, acc[3][2]); acc[3][3] = fmaf(a.w, b.w, acc[3][3]);
        }
        if (s < 7) { ra[0] = na[0]; ra[1] = na[1]; rb[0] = nb[0]; rb[1] = nb[1]; }
      }
      __syncthreads();
#pragma unroll
      for (int i = 0; i < 4; ++i)
#pragma unroll
        for (int j = 0; j < 4; ++j)
          smem[w * 1024 + (rg * 4 + i) * 32 + cg * 4 + j] = acc[i][j];
      __syncthreads();

      if (tid < 256) {
        float gv[4];
#pragma unroll
        for (int g = 0; g < 4; ++g) {
          float s_ = bsr[g];
          const int j = g * 8 + qlc;
#pragma unroll
          for (int w2 = 0; w2 < 8; ++w2) s_ += smem[w2 * 1024 + mlc * 32 + j];
          gv[g] = s_;
        }
        const float cn = sigf(gv[1]) * creg + sigf(gv[0]) * tanhf(gv[2]);
        creg = cn;
        hWrite[hIdx] = sigf(gv[3]) * tanhf(cn);
      }
    }
    grid_barrier(bar);

    // ---------------- phase B: logits + argmax partials ----------------
    {
      float acc[2][4];
#pragma unroll
      for (int i = 0; i < 2; ++i)
#pragma unroll
        for (int j = 0; j < 4; ++j) acc[i][j] = 0.f;

      float4 ra; float4 rb[2];
      auto loadA2 = [&](int s, float4& r) {
        r = *(const float4*)(hWrite + (size_t)(m0B + amB) * H_SZ + kbB + s * 16 + afA);
      };
      auto loadB2 = [&](int s, float4* r) {
#pragma unroll
        for (int i = 0; i < 2; ++i)
          r[i] = *(const float4*)(WoT + (size_t)(kbB + s * 16 + bkA + i * 8) * VP + n0B + bnA);
      };

      loadA2(0, ra); loadB2(0, rb);
#pragma unroll 1
      for (int s = 0; s < 4; ++s) {
        As2[(afA + 0) * 20 + amB] = ra.x;
        As2[(afA + 1) * 20 + amB] = ra.y;
        As2[(afA + 2) * 20 + amB] = ra.z;
        As2[(afA + 3) * 20 + amB] = ra.w;
#pragma unroll
        for (int i = 0; i < 2; ++i) *(float4*)(Bs2 + (bkA + i * 8) * 36 + bnA) = rb[i];
        float4 na; float4 nb[2];
        if (s < 3) { loadA2(s + 1, na); loadB2(s + 1, nb); }
#pragma unroll
        for (int k = 0; k < 16; ++k) {
          float2 a = *(const float2*)(As2 + k * 20 + rg * 2);
          float4 b = *(const float4*)(Bs2 + k * 36 + cg * 4);
          acc[0][0] = fmaf(a.x, b.x, acc[0][0]); acc[0][1] = fmaf(a.x, b.y, acc[0][1]);
          acc[0][2] = fmaf(a.x, b.z, acc[0][2]); acc[0][3] = fmaf(a.x, b.w, acc[0][3]);
          acc[1][0] = fmaf(a.y, b.x, acc[1][0]); acc[1][1] = fmaf(a.y, b.y, acc[1][1]);
          acc[1][2] = fmaf(a.y, b.z, acc[1][2]); acc[1][3] = fmaf(a.y, b.w, acc[1][3]);
        }
        if (s < 3) { ra = na; rb[0] = nb[0]; rb[1] = nb[1]; }
      }
      __syncthreads();
#pragma unroll
      for (int i = 0; i < 2; ++i)
#pragma unroll
        for (int j = 0; j < 4; ++j)
          smem[w * 512 + (rg * 2 + i) * 32 + cg * 4 + j] = acc[i][j];
      __syncthreads();

      float sres = bor;
#pragma unroll
      for (int w2 = 0; w2 < 8; ++w2) sres += smem[w2 * 512 + tid];
      u64 p = 0ull;
      if (ngB < V_SZ) {
        out[outBase + (size_t)t * V_SZ] = sres;
        p = ((u64)fkey(sres) << 32) | (u64)(unsigned)(~(unsigned)ngB);
      }
#pragma unroll
      for (int d = 16; d >= 1; d >>= 1) {
        u64 o = __shfl_xor(p, d, 64);
        p = (o > p) ? o : p;
      }
      if (nlb == 0) pk[(size_t)mgB * 32 + vt] = p;
    }
    grid_barrier(bar);
  }

  // ---------------- final h, c tail ----------------
  const size_t off = (size_t)B_SZ * T_SZ * V_SZ;
  {
    // h final lives in h0buf (t=255 wrote h0)
    const int i = bid * 256 + ((tid < 256) ? tid : (tid - 256));
    if (tid < 256) out[off + (size_t)bid * 256 + tid] = h0buf[(size_t)bid * 256 + tid];
    (void)i;
    // c from registers: owner thread writes its cell
    if (tid < 256) out[off + 65536 + hIdx] = creg;
  }
}

// ---------------- launcher ----------------
extern "C" void kernel_launch(void* const* d_in, const int* in_sizes, int n_in,
                              void* d_out, int out_size, void* d_ws, size_t ws_size,
                              hipStream_t stream) {
  (void)in_sizes; (void)n_in; (void)out_size; (void)ws_size;
  const float* ctx   = (const float*)d_in[0];
  const int*   tgt   = (const int*)d_in[1];
  const float* coin  = (const float*)d_in[2];
  const float* etbl  = (const float*)d_in[3];
  const float* W_ih  = (const float*)d_in[4];
  const float* W_hh  = (const float*)d_in[5];
  const float* b_ih  = (const float*)d_in[6];
  const float* b_hh  = (const float*)d_in[7];
  const float* W_out = (const float*)d_in[8];
  const float* b_out = (const float*)d_in[9];
  float* out = (float*)d_out;

  float* ws    = (float*)d_ws;
  float* Wt    = ws;                       // 1024*2048  (rows 0..511: W_ih emb cols; 512..1023: W_hh)
  float* Wtc   = Wt + 2097152;             // 512*2048   (W_ih ctx cols, transposed)
  float* WoT   = Wtc + 1048576;            // 512*1024   (zero-padded cols >= 1000)
  float* base  = WoT + 524288;             // 128*2048
  float* h0    = base + 262144;            // 128*512
  float* h1    = h0 + 65536;               // 128*512
  u64*   pk    = (u64*)(h1 + 65536);       // 128*32 packed argmax partials
  float* bo    = (float*)(pk + 4096);      // 1024 padded b_out
  unsigned* bar = (unsigned*)(bo + 1024);  // 64 uints barrier state

  hipLaunchKernelGGL(k_transpose, dim3(64, 16), dim3(256), 0, stream,
                     W_ih, 1024, 512, Wt, NG, 2048);
  hipLaunchKernelGGL(k_transpose, dim3(64, 16), dim3(256), 0, stream,
                     W_hh, 512, 0, Wt + (size_t)512 * NG, NG, 2048);
  hipLaunchKernelGGL(k_transpose, dim3(64, 16), dim3(256), 0, stream,
                     W_ih, 1024, 0, Wtc, NG, 2048);
  hipLaunchKernelGGL(k_transpose, dim3(32, 16), dim3(256), 0, stream,
                     W_out, 512, 0, WoT, VP, 1000);
  hipLaunchKernelGGL(k_base, dim3(64, 4), dim3(256), 0, stream, ctx, Wtc, b_ih, b_hh, base);
  hipLaunchKernelGGL(k_init, dim3(256), dim3(256), 0, stream, ctx, b_out, h0, bo, bar);

  void* args[] = { (void*)&Wt, (void*)&WoT, (void*)&base, (void*)&etbl, (void*)&coin,
                   (void*)&tgt, (void*)&bo, (void*)&h0, (void*)&h1, (void*)&out,
                   (void*)&pk, (void*)&bar };
  hipLaunchCooperativeKernel((void*)k_persist, dim3(256), dim3(512), args, 0, stream);
}

// Round 4
// 12031.730 us; speedup vs baseline: 1.3513x; 1.3513x over previous
//
#include <hip/hip_runtime.h>
#include <cstdint>
#include <cstddef>

#define B_SZ 128
#define T_SZ 256
#define V_SZ 1000
#define H_SZ 512
#define NG   2048   // 4*H
#define VP   1024   // padded V

typedef unsigned long long u64;

__device__ __forceinline__ unsigned fkey(float f) {
  unsigned u = __float_as_uint(f);
  return (u & 0x80000000u) ? ~u : (u | 0x80000000u);
}
__device__ __forceinline__ float sigf(float x) { return 1.0f / (1.0f + expf(-x)); }

// ---- agent-scope (cross-XCD coherent) accessors: bypass L1/L2, served by LLC ----
__device__ __forceinline__ float aload(const float* p) {
  return __hip_atomic_load(p, __ATOMIC_RELAXED, __HIP_MEMORY_SCOPE_AGENT);
}
__device__ __forceinline__ float4 aload4(const float* p) {
  float4 r;
  r.x = __hip_atomic_load(p + 0, __ATOMIC_RELAXED, __HIP_MEMORY_SCOPE_AGENT);
  r.y = __hip_atomic_load(p + 1, __ATOMIC_RELAXED, __HIP_MEMORY_SCOPE_AGENT);
  r.z = __hip_atomic_load(p + 2, __ATOMIC_RELAXED, __HIP_MEMORY_SCOPE_AGENT);
  r.w = __hip_atomic_load(p + 3, __ATOMIC_RELAXED, __HIP_MEMORY_SCOPE_AGENT);
  return r;
}
__device__ __forceinline__ void astore(float* p, float v) {
  __hip_atomic_store(p, v, __ATOMIC_RELAXED, __HIP_MEMORY_SCOPE_AGENT);
}
__device__ __forceinline__ u64 aload64(const u64* p) {
  return __hip_atomic_load(p, __ATOMIC_RELAXED, __HIP_MEMORY_SCOPE_AGENT);
}
__device__ __forceinline__ void astore64(u64* p, u64 v) {
  __hip_atomic_store(p, v, __ATOMIC_RELAXED, __HIP_MEMORY_SCOPE_AGENT);
}

// ---- flag-based grid barrier: no RMW contention, no L2 invalidation ----
// arrive[256] unpadded; each block stores gen to its own word; wave0 polls all.
// The release store orders this block's prior agent-scope (sc1) data stores:
// they are complete at LLC before the flag becomes visible.
__device__ __forceinline__ void flag_barrier(unsigned* arrive, unsigned gen) {
  __syncthreads();
  if (threadIdx.x == 0)
    __hip_atomic_store(arrive + blockIdx.x, gen, __ATOMIC_RELEASE, __HIP_MEMORY_SCOPE_AGENT);
  if (threadIdx.x < 64) {
    const int base = threadIdx.x * 4;
    for (;;) {
      bool ok = true;
#pragma unroll
      for (int j = 0; j < 4; ++j)
        ok &= (__hip_atomic_load(arrive + base + j, __ATOMIC_RELAXED,
                                 __HIP_MEMORY_SCOPE_AGENT) >= gen);
      if (__all(ok)) break;
      __builtin_amdgcn_s_sleep(2);
    }
  }
  __syncthreads();
}

// ---------------- one-time kernels ----------------

// dst[k][n] = (n < n_valid) ? src[n*srcLD + col_off + k] : 0
__global__ void k_transpose(const float* __restrict__ src, int srcLD, int col_off,
                            float* __restrict__ dst, int dstLD, int n_valid) {
  __shared__ float tile[32][33];
  const int tid = threadIdx.x;
  const int k0 = blockIdx.y * 32, n0 = blockIdx.x * 32;
  const int nl = tid >> 3, kq = (tid & 7) * 4;
  float4 v = make_float4(0.f, 0.f, 0.f, 0.f);
  if (n0 + nl < n_valid)
    v = *(const float4*)(src + (size_t)(n0 + nl) * srcLD + col_off + k0 + kq);
  tile[nl][kq + 0] = v.x; tile[nl][kq + 1] = v.y;
  tile[nl][kq + 2] = v.z; tile[nl][kq + 3] = v.w;
  __syncthreads();
  const int kl = tid >> 3, nq = (tid & 7) * 4;
  float4 o;
  o.x = tile[nq + 0][kl]; o.y = tile[nq + 1][kl];
  o.z = tile[nq + 2][kl]; o.w = tile[nq + 3][kl];
  *(float4*)(dst + (size_t)(k0 + kl) * dstLD + n0 + nq) = o;
}

// base[m][n] = sum_k ctx[m][k] * Wtc[k][n] + b_ih[n] + b_hh[n]
__global__ void k_base(const float* __restrict__ ctx, const float* __restrict__ Wtc,
                       const float* __restrict__ b_ih, const float* __restrict__ b_hh,
                       float* __restrict__ base) {
  const int tid = threadIdx.x;
  const int n0 = blockIdx.x * 32, m0 = blockIdx.y * 32;
  const int ml = tid >> 3, ng = (tid & 7) * 4;
  const float* a = ctx + (size_t)(m0 + ml) * H_SZ;
  const float* b = Wtc + n0 + ng;
  float acc0 = 0.f, acc1 = 0.f, acc2 = 0.f, acc3 = 0.f;
#pragma unroll 4
  for (int k = 0; k < H_SZ; ++k) {
    float av = a[k];
    float4 bv = *(const float4*)(b + (size_t)k * NG);
    acc0 = fmaf(av, bv.x, acc0); acc1 = fmaf(av, bv.y, acc1);
    acc2 = fmaf(av, bv.z, acc2); acc3 = fmaf(av, bv.w, acc3);
  }
  const int n = n0 + ng;
  float* o = base + (size_t)(m0 + ml) * NG + n;
  o[0] = acc0 + b_ih[n + 0] + b_hh[n + 0];
  o[1] = acc1 + b_ih[n + 1] + b_hh[n + 1];
  o[2] = acc2 + b_ih[n + 2] + b_hh[n + 2];
  o[3] = acc3 + b_ih[n + 3] + b_hh[n + 3];
}

__global__ void k_init(const float* __restrict__ ctx, const float* __restrict__ b_out,
                       float* __restrict__ h0, float* __restrict__ bo,
                       unsigned* __restrict__ arrive) {
  const int i = blockIdx.x * 256 + threadIdx.x;   // 65536 total
  h0[i] = ctx[i];
  if (i < VP) bo[i] = (i < V_SZ) ? b_out[i] : 0.f;
  if (i < 256) arrive[i] = 0u;
}

// ---------------- persistent cooperative kernel ----------------
// 256 blocks x 512 threads. Per step:
//   phase A: gates GEMM (32m x 8q x 4gates, K=1024, 8-wave K-split) + fused LSTM cell
//   h-barrier
//   phase B: logits GEMM (16m x 32v, K=512, 8-wave K-split) + out + argmax partials
//   pk-barrier ONLY if step t+1 takes the argmax-feedback path
__global__ __launch_bounds__(512, 2) void k_persist(
    const float* __restrict__ Wt, const float* __restrict__ WoT,
    const float* __restrict__ base, const float* __restrict__ etbl,
    const float* __restrict__ coin, const int* __restrict__ tgt,
    const float* __restrict__ bo, float* __restrict__ h0buf, float* __restrict__ h1buf,
    float* __restrict__ out, u64* __restrict__ pk, unsigned* __restrict__ arrive) {
  __shared__ float smem[9216];
  __shared__ int idx_s[32];
  const int tid = threadIdx.x;
  const int bid = blockIdx.x;
  const int xcd = bid & 7, slot = bid >> 3;

  // phase A tiling: qtiles grouped per XCD for W L2-residency (1MB/XCD)
  const int qt = xcd * 8 + (slot >> 2);     // 0..63
  const int mtA = slot & 3;                 // 0..3
  const int q0 = qt * 8, m0A = mtA * 32;
  // phase B tiling: vtiles grouped per XCD (WoT slice 256KB/XCD)
  const int vt = xcd * 4 + (slot & 3);      // 0..31
  const int mtB = slot >> 2;                // 0..7
  const int n0B = vt * 32, m0B = mtB * 16;

  const int w = tid >> 6, lane = tid & 63;
  const int rg = lane >> 3, cg = lane & 7;
  float* As = smem + w * 1152;              // [16k][32m] pad36
  float* Bs = As + 576;                     // [16k][32j] pad36
  const int kbA = w * 128;
  const int amA = lane >> 2, afA = (lane & 3) * 4;
  const int bkA = lane >> 3;
  const int bnA = (lane & 7) * 4;
  const int colA = (bnA >> 3) * 512 + q0 + (bnA & 7);
  float* As2 = smem + w * 896;              // [16k][16m] pad20
  float* Bs2 = As2 + 320;                   // [16k][32n] pad36
  const int kbB = w * 64;
  const int amB = lane >> 2;

  // cell-thread constants + preloaded base (loop-invariant, L2-resident)
  const int mlc = tid >> 3, qlc = tid & 7;
  float bsr[4];
  size_t hIdx = 0;
  if (tid < 256) {
#pragma unroll
    for (int g = 0; g < 4; ++g)
      bsr[g] = base[(size_t)(m0A + mlc) * NG + g * 512 + q0 + qlc];
    hIdx = (size_t)(m0A + mlc) * H_SZ + q0 + qlc;
  }
  float creg = 0.f;  // persistent cell state

  // phase B epilogue constants
  const int mlb = tid >> 5, nlb = tid & 31;
  const int ngB = n0B + nlb, mgB = m0B + mlb;
  const float bor = bo[ngB];
  const size_t outBase = (size_t)mgB * ((size_t)T_SZ * V_SZ) + ngB;

  unsigned gen = 0;

#pragma unroll 1
  for (int t = 0; t < T_SZ; ++t) {
    const float* hRead  = (t & 1) ? h1buf : h0buf;
    float*       hWrite = (t & 1) ? h0buf : h1buf;

    // ---------------- phase A: gates + cell ----------------
    if (tid < 32) {
      int id = 0;
      if (t > 0) {
        if (coin[t] > 0.5f) {
          id = tgt[(m0A + tid) * T_SZ + (t - 1)];
        } else {
          const u64* p = pk + (size_t)(m0A + tid) * 32;
          u64 best = 0ull;
#pragma unroll
          for (int q = 0; q < 32; ++q) { u64 v = aload64(p + q); best = (v > best) ? v : best; }
          id = (int)(~(unsigned)best);
        }
      }
      idx_s[tid] = id;
    }
    __syncthreads();

    {
      float acc[4][4];
#pragma unroll
      for (int i = 0; i < 4; ++i)
#pragma unroll
        for (int j = 0; j < 4; ++j) acc[i][j] = 0.f;

      float4 ra[2], rb[2];
      auto loadA = [&](int s, float4* r) {
        const int k = kbA + s * 16 + afA;
#pragma unroll
        for (int i = 0; i < 2; ++i) {
          const int m_ = amA + i * 16;
          if (k < 512)
            r[i] = *(const float4*)(etbl + (size_t)idx_s[m_] * 512 + k);
          else
            r[i] = aload4(hRead + (size_t)(m0A + m_) * H_SZ + (k - 512));
        }
      };
      auto loadB = [&](int s, float4* r) {
#pragma unroll
        for (int i = 0; i < 2; ++i)
          r[i] = *(const float4*)(Wt + (size_t)(kbA + s * 16 + bkA + i * 8) * NG + colA);
      };

      loadA(0, ra); loadB(0, rb);
#pragma unroll 1
      for (int s = 0; s < 8; ++s) {
#pragma unroll
        for (int i = 0; i < 2; ++i) {
          const int m_ = amA + i * 16;
          As[(afA + 0) * 36 + m_] = ra[i].x;
          As[(afA + 1) * 36 + m_] = ra[i].y;
          As[(afA + 2) * 36 + m_] = ra[i].z;
          As[(afA + 3) * 36 + m_] = ra[i].w;
          *(float4*)(Bs + (bkA + i * 8) * 36 + bnA) = rb[i];
        }
        float4 na[2], nb[2];
        if (s < 7) { loadA(s + 1, na); loadB(s + 1, nb); }
#pragma unroll
        for (int k = 0; k < 16; ++k) {
          float4 a = *(const float4*)(As + k * 36 + rg * 4);
          float4 b = *(const float4*)(Bs + k * 36 + cg * 4);
          acc[0][0] = fmaf(a.x, b.x, acc[0][0]); acc[0][1] = fmaf(a.x, b.y, acc[0][1]);
          acc[0][2] = fmaf(a.x, b.z, acc[0][2]); acc[0][3] = fmaf(a.x, b.w, acc[0][3]);
          acc[1][0] = fmaf(a.y, b.x, acc[1][0]); acc[1][1] = fmaf(a.y, b.y, acc[1][1]);
          acc[1][2] = fmaf(a.y, b.z, acc[1][2]); acc[1][3] = fmaf(a.y, b.w, acc[1][3]);
          acc[2][0] = fmaf(a.z, b.x, acc[2][0]); acc[2][1] = fmaf(a.z, b.y, acc[2][1]);
          acc[2][2] = fmaf(a.z, b.z, acc[2][2]); acc[2][3] = fmaf(a.z, b.w, acc[2][3]);
          acc[3][0] = fmaf(a.w, b.x, acc[3][0]); acc[3][1] = fmaf(a.w, b.y, acc[3][1]);
          acc[3][2] = fmaf(a.w, b.z, acc[3][2]); acc[3][3] = fmaf(a.w, b.w, acc[3][3]);
        }
        if (s < 7) { ra[0] = na[0]; ra[1] = na[1]; rb[0] = nb[0]; rb[1] = nb[1]; }
      }
      __syncthreads();
#pragma unroll
      for (int i = 0; i < 4; ++i)
#pragma unroll
        for (int j = 0; j < 4; ++j)
          smem[w * 1024 + (rg * 4 + i) * 32 + cg * 4 + j] = acc[i][j];
      __syncthreads();

      if (tid < 256) {
        float gv[4];
#pragma unroll
        for (int g = 0; g < 4; ++g) {
          float s_ = bsr[g];
          const int j = g * 8 + qlc;
#pragma unroll
          for (int w2 = 0; w2 < 8; ++w2) s_ += smem[w2 * 1024 + mlc * 32 + j];
          gv[g] = s_;
        }
        const float cn = sigf(gv[1]) * creg + sigf(gv[0]) * tanhf(gv[2]);
        creg = cn;
        astore(hWrite + hIdx, sigf(gv[3]) * tanhf(cn));
      }
    }
    flag_barrier(arrive, ++gen);

    // ---------------- phase B: logits + argmax partials ----------------
    {
      float acc[2][4];
#pragma unroll
      for (int i = 0; i < 2; ++i)
#pragma unroll
        for (int j = 0; j < 4; ++j) acc[i][j] = 0.f;

      float4 ra; float4 rb[2];
      auto loadA2 = [&](int s, float4& r) {
        r = aload4(hWrite + (size_t)(m0B + amB) * H_SZ + kbB + s * 16 + afA);
      };
      auto loadB2 = [&](int s, float4* r) {
#pragma unroll
        for (int i = 0; i < 2; ++i)
          r[i] = *(const float4*)(WoT + (size_t)(kbB + s * 16 + bkA + i * 8) * VP + n0B + bnA);
      };

      loadA2(0, ra); loadB2(0, rb);
#pragma unroll 1
      for (int s = 0; s < 4; ++s) {
        As2[(afA + 0) * 20 + amB] = ra.x;
        As2[(afA + 1) * 20 + amB] = ra.y;
        As2[(afA + 2) * 20 + amB] = ra.z;
        As2[(afA + 3) * 20 + amB] = ra.w;
#pragma unroll
        for (int i = 0; i < 2; ++i) *(float4*)(Bs2 + (bkA + i * 8) * 36 + bnA) = rb[i];
        float4 na; float4 nb[2];
        if (s < 3) { loadA2(s + 1, na); loadB2(s + 1, nb); }
#pragma unroll
        for (int k = 0; k < 16; ++k) {
          float2 a = *(const float2*)(As2 + k * 20 + rg * 2);
          float4 b = *(const float4*)(Bs2 + k * 36 + cg * 4);
          acc[0][0] = fmaf(a.x, b.x, acc[0][0]); acc[0][1] = fmaf(a.x, b.y, acc[0][1]);
          acc[0][2] = fmaf(a.x, b.z, acc[0][2]); acc[0][3] = fmaf(a.x, b.w, acc[0][3]);
          acc[1][0] = fmaf(a.y, b.x, acc[1][0]); acc[1][1] = fmaf(a.y, b.y, acc[1][1]);
          acc[1][2] = fmaf(a.y, b.z, acc[1][2]); acc[1][3] = fmaf(a.y, b.w, acc[1][3]);
        }
        if (s < 3) { ra = na; rb[0] = nb[0]; rb[1] = nb[1]; }
      }
      __syncthreads();
#pragma unroll
      for (int i = 0; i < 2; ++i)
#pragma unroll
        for (int j = 0; j < 4; ++j)
          smem[w * 512 + (rg * 2 + i) * 32 + cg * 4 + j] = acc[i][j];
      __syncthreads();

      float sres = bor;
#pragma unroll
      for (int w2 = 0; w2 < 8; ++w2) sres += smem[w2 * 512 + tid];
      u64 p = 0ull;
      if (ngB < V_SZ) {
        out[outBase + (size_t)t * V_SZ] = sres;
        p = ((u64)fkey(sres) << 32) | (u64)(unsigned)(~(unsigned)ngB);
      }
#pragma unroll
      for (int d = 16; d >= 1; d >>= 1) {
        u64 o = __shfl_xor(p, d, 64);
        p = (o > p) ? o : p;
      }
      if (nlb == 0) astore64(pk + (size_t)mgB * 32 + vt, p);
    }
    // pk is only read at step t+1 when that step takes the argmax path
    const bool need_pk_bar = (t + 1 < T_SZ) && !(coin[t + 1] > 0.5f);
    if (need_pk_bar) flag_barrier(arrive, ++gen);
  }

  // ---------------- final h, c tail ----------------
  const size_t off = (size_t)B_SZ * T_SZ * V_SZ;
  if (tid < 256) {
    out[off + (size_t)bid * 256 + tid] = aload(h0buf + (size_t)bid * 256 + tid);
    out[off + 65536 + hIdx] = creg;
  }
}

// ---------------- launcher ----------------
extern "C" void kernel_launch(void* const* d_in, const int* in_sizes, int n_in,
                              void* d_out, int out_size, void* d_ws, size_t ws_size,
                              hipStream_t stream) {
  (void)in_sizes; (void)n_in; (void)out_size; (void)ws_size;
  const float* ctx   = (const float*)d_in[0];
  const int*   tgt   = (const int*)d_in[1];
  const float* coin  = (const float*)d_in[2];
  const float* etbl  = (const float*)d_in[3];
  const float* W_ih  = (const float*)d_in[4];
  const float* W_hh  = (const float*)d_in[5];
  const float* b_ih  = (const float*)d_in[6];
  const float* b_hh  = (const float*)d_in[7];
  const float* W_out = (const float*)d_in[8];
  const float* b_out = (const float*)d_in[9];
  float* out = (float*)d_out;

  float* ws    = (float*)d_ws;
  float* Wt    = ws;                       // 1024*2048
  float* Wtc   = Wt + 2097152;             // 512*2048
  float* WoT   = Wtc + 1048576;            // 512*1024 (zero-padded cols >= 1000)
  float* base  = WoT + 524288;             // 128*2048
  float* h0    = base + 262144;            // 128*512
  float* h1    = h0 + 65536;               // 128*512
  u64*   pk    = (u64*)(h1 + 65536);       // 128*32 packed argmax partials
  float* bo    = (float*)(pk + 4096);      // 1024 padded b_out
  unsigned* arrive = (unsigned*)(bo + 1024); // 256 flags

  hipLaunchKernelGGL(k_transpose, dim3(64, 16), dim3(256), 0, stream,
                     W_ih, 1024, 512, Wt, NG, 2048);
  hipLaunchKernelGGL(k_transpose, dim3(64, 16), dim3(256), 0, stream,
                     W_hh, 512, 0, Wt + (size_t)512 * NG, NG, 2048);
  hipLaunchKernelGGL(k_transpose, dim3(64, 16), dim3(256), 0, stream,
                     W_ih, 1024, 0, Wtc, NG, 2048);
  hipLaunchKernelGGL(k_transpose, dim3(32, 16), dim3(256), 0, stream,
                     W_out, 512, 0, WoT, VP, 1000);
  hipLaunchKernelGGL(k_base, dim3(64, 4), dim3(256), 0, stream, ctx, Wtc, b_ih, b_hh, base);
  hipLaunchKernelGGL(k_init, dim3(256), dim3(256), 0, stream, ctx, b_out, h0, bo, arrive);

  void* args[] = { (void*)&Wt, (void*)&WoT, (void*)&base, (void*)&etbl, (void*)&coin,
                   (void*)&tgt, (void*)&bo, (void*)&h0, (void*)&h1, (void*)&out,
                   (void*)&pk, (void*)&arrive };
  hipLaunchCooperativeKernel((void*)k_persist, dim3(256), dim3(512), args, 0, stream);
}

// Round 6
// 10264.759 us; speedup vs baseline: 1.5839x; 1.1721x over previous
//
#include <hip/hip_runtime.h>
#include <cstdint>
#include <cstddef>

#define B_SZ 128
#define T_SZ 256
#define V_SZ 1000
#define H_SZ 512
#define NG   2048   // 4*H
#define VP   1024   // padded V

typedef unsigned long long u64;

__device__ __forceinline__ unsigned fkey(float f) {
  unsigned u = __float_as_uint(f);
  return (u & 0x80000000u) ? ~u : (u | 0x80000000u);
}
__device__ __forceinline__ float sigf(float x) { return 1.0f / (1.0f + expf(-x)); }

// ---- agent-scope (cross-XCD coherent) accessors: bypass L1/L2, served by LLC ----
__device__ __forceinline__ float aload(const float* p) {
  return __hip_atomic_load(p, __ATOMIC_RELAXED, __HIP_MEMORY_SCOPE_AGENT);
}
__device__ __forceinline__ float4 aload4(const float* p) {
  float4 r;
  r.x = __hip_atomic_load(p + 0, __ATOMIC_RELAXED, __HIP_MEMORY_SCOPE_AGENT);
  r.y = __hip_atomic_load(p + 1, __ATOMIC_RELAXED, __HIP_MEMORY_SCOPE_AGENT);
  r.z = __hip_atomic_load(p + 2, __ATOMIC_RELAXED, __HIP_MEMORY_SCOPE_AGENT);
  r.w = __hip_atomic_load(p + 3, __ATOMIC_RELAXED, __HIP_MEMORY_SCOPE_AGENT);
  return r;
}
__device__ __forceinline__ void astore(float* p, float v) {
  __hip_atomic_store(p, v, __ATOMIC_RELAXED, __HIP_MEMORY_SCOPE_AGENT);
}
__device__ __forceinline__ u64 aload64(const u64* p) {
  return __hip_atomic_load(p, __ATOMIC_RELAXED, __HIP_MEMORY_SCOPE_AGENT);
}
__device__ __forceinline__ void astore64(u64* p, u64 v) {
  __hip_atomic_store(p, v, __ATOMIC_RELAXED, __HIP_MEMORY_SCOPE_AGENT);
}

// ---- broadcast barrier: relaxed flags only, no release (no L2 writeback), ----
// ---- block0 aggregates 256 arrive flags, publishes single go word (idx 320) ----
// Ordering: __syncthreads() drains vmcnt for every wave (compiler-emitted full
// waitcnt before s_barrier), so all this block's sc1 data stores are acked at
// LLC before tid0 issues the flag store.
__device__ __forceinline__ void bcast_barrier(unsigned* arrive, unsigned gen) {
  __syncthreads();
  if (threadIdx.x == 0)
    __hip_atomic_store(arrive + blockIdx.x, gen, __ATOMIC_RELAXED, __HIP_MEMORY_SCOPE_AGENT);
  if (blockIdx.x == 0 && threadIdx.x < 64) {
    const int base = threadIdx.x * 4;
    for (;;) {
      bool ok = true;
#pragma unroll
      for (int j = 0; j < 4; ++j)
        ok &= (__hip_atomic_load(arrive + base + j, __ATOMIC_RELAXED,
                                 __HIP_MEMORY_SCOPE_AGENT) >= gen);
      if (__all(ok)) break;
      __builtin_amdgcn_s_sleep(2);
    }
    if (threadIdx.x == 0)
      __hip_atomic_store(arrive + 320, gen, __ATOMIC_RELAXED, __HIP_MEMORY_SCOPE_AGENT);
  }
  if (threadIdx.x == 0) {
    while (__hip_atomic_load(arrive + 320, __ATOMIC_RELAXED,
                             __HIP_MEMORY_SCOPE_AGENT) < gen)
      __builtin_amdgcn_s_sleep(2);
  }
  __syncthreads();
}

// ---------------- one-time kernels ----------------

// dst[k][n] = (n < n_valid) ? src[n*srcLD + col_off + k] : 0
__global__ void k_transpose(const float* __restrict__ src, int srcLD, int col_off,
                            float* __restrict__ dst, int dstLD, int n_valid) {
  __shared__ float tile[32][33];
  const int tid = threadIdx.x;
  const int k0 = blockIdx.y * 32, n0 = blockIdx.x * 32;
  const int nl = tid >> 3, kq = (tid & 7) * 4;
  float4 v = make_float4(0.f, 0.f, 0.f, 0.f);
  if (n0 + nl < n_valid)
    v = *(const float4*)(src + (size_t)(n0 + nl) * srcLD + col_off + k0 + kq);
  tile[nl][kq + 0] = v.x; tile[nl][kq + 1] = v.y;
  tile[nl][kq + 2] = v.z; tile[nl][kq + 3] = v.w;
  __syncthreads();
  const int kl = tid >> 3, nq = (tid & 7) * 4;
  float4 o;
  o.x = tile[nq + 0][kl]; o.y = tile[nq + 1][kl];
  o.z = tile[nq + 2][kl]; o.w = tile[nq + 3][kl];
  *(float4*)(dst + (size_t)(k0 + kl) * dstLD + n0 + nq) = o;
}

// base[m][n] = sum_k ctx[m][k] * Wtc[k][n] + b_ih[n] + b_hh[n]
__global__ void k_base(const float* __restrict__ ctx, const float* __restrict__ Wtc,
                       const float* __restrict__ b_ih, const float* __restrict__ b_hh,
                       float* __restrict__ base) {
  const int tid = threadIdx.x;
  const int n0 = blockIdx.x * 32, m0 = blockIdx.y * 32;
  const int ml = tid >> 3, ng = (tid & 7) * 4;
  const float* a = ctx + (size_t)(m0 + ml) * H_SZ;
  const float* b = Wtc + n0 + ng;
  float acc0 = 0.f, acc1 = 0.f, acc2 = 0.f, acc3 = 0.f;
#pragma unroll 4
  for (int k = 0; k < H_SZ; ++k) {
    float av = a[k];
    float4 bv = *(const float4*)(b + (size_t)k * NG);
    acc0 = fmaf(av, bv.x, acc0); acc1 = fmaf(av, bv.y, acc1);
    acc2 = fmaf(av, bv.z, acc2); acc3 = fmaf(av, bv.w, acc3);
  }
  const int n = n0 + ng;
  float* o = base + (size_t)(m0 + ml) * NG + n;
  o[0] = acc0 + b_ih[n + 0] + b_hh[n + 0];
  o[1] = acc1 + b_ih[n + 1] + b_hh[n + 1];
  o[2] = acc2 + b_ih[n + 2] + b_hh[n + 2];
  o[3] = acc3 + b_ih[n + 3] + b_hh[n + 3];
}

__global__ void k_init(const float* __restrict__ ctx, const float* __restrict__ b_out,
                       float* __restrict__ h0, float* __restrict__ bo,
                       unsigned* __restrict__ arrive) {
  const int i = blockIdx.x * 256 + threadIdx.x;   // 65536 total
  h0[i] = ctx[i];
  if (i < VP) bo[i] = (i < V_SZ) ? b_out[i] : 0.f;
  if (i < 512) arrive[i] = 0u;
}

// ---------------- persistent cooperative kernel ----------------
// 256 blocks x 512 threads. Per step (ONE grid barrier):
//   phase A: idx via pk tag-spin -> gates GEMM (32m x 8q x 4gates, K=1024,
//            8-wave K-split) + fused LSTM cell (c in registers)
//   h-barrier (broadcast)
//   phase B: logits GEMM (16m x 32v, K=512, 8-wave K-split) + out + tagged pk
// pk anti-overwrite WAR is protected by the mid-step barrier; pk RAW is the
// tag spin. h double-buffer WAR protected by next step's barrier.
__global__ __launch_bounds__(512, 2) void k_persist(
    const float* __restrict__ Wt, const float* __restrict__ WoT,
    const float* __restrict__ base, const float* __restrict__ etbl,
    const float* __restrict__ coin, const int* __restrict__ tgt,
    const float* __restrict__ bo, float* __restrict__ h0buf, float* __restrict__ h1buf,
    float* __restrict__ out, u64* __restrict__ pk, unsigned* __restrict__ arrive) {
  __shared__ float smem[9216];
  __shared__ int idx_s[32];
  const int tid = threadIdx.x;
  const int bid = blockIdx.x;
  const int xcd = bid & 7, slot = bid >> 3;

  // phase A tiling: qtiles grouped per XCD for W L2-residency (1MB/XCD)
  const int qt = xcd * 8 + (slot >> 2);     // 0..63
  const int mtA = slot & 3;                 // 0..3
  const int q0 = qt * 8, m0A = mtA * 32;
  // phase B tiling: vtiles grouped per XCD (WoT slice 256KB/XCD)
  const int vt = xcd * 4 + (slot & 3);      // 0..31
  const int mtB = slot >> 2;                // 0..7
  const int n0B = vt * 32, m0B = mtB * 16;

  const int w = tid >> 6, lane = tid & 63;
  const int rg = lane >> 3, cg = lane & 7;
  float* As = smem + w * 1152;              // [16k][32m] pad36
  float* Bs = As + 576;                     // [16k][32j] pad36
  const int kbA = w * 128;
  const int amA = lane >> 2, afA = (lane & 3) * 4;
  const int bkA = lane >> 3;
  const int bnA = (lane & 7) * 4;
  const int colA = (bnA >> 3) * 512 + q0 + (bnA & 7);
  float* As2 = smem + w * 896;              // [16k][16m] pad20
  float* Bs2 = As2 + 320;                   // [16k][32n] pad36
  const int kbB = w * 64;
  const int amB = lane >> 2;

  // cell-thread constants + preloaded base (loop-invariant, L2-resident)
  const int mlc = tid >> 3, qlc = tid & 7;
  float bsr[4];
  size_t hIdx = 0;
  if (tid < 256) {
#pragma unroll
    for (int g = 0; g < 4; ++g)
      bsr[g] = base[(size_t)(m0A + mlc) * NG + g * 512 + q0 + qlc];
    hIdx = (size_t)(m0A + mlc) * H_SZ + q0 + qlc;
  }
  float creg = 0.f;  // persistent cell state

  // phase B epilogue constants
  const int mlb = tid >> 5, nlb = tid & 31;
  const int ngB = n0B + nlb, mgB = m0B + mlb;
  const float bor = bo[ngB];
  const size_t outBase = (size_t)mgB * ((size_t)T_SZ * V_SZ) + ngB;

#pragma unroll 1
  for (int t = 0; t < T_SZ; ++t) {
    const float* hRead  = (t & 1) ? h1buf : h0buf;
    float*       hWrite = (t & 1) ? h0buf : h1buf;

    // ---------------- phase A: gates + cell ----------------
    if (tid < 32) {
      int id = 0;
      if (t > 0) {
        if (coin[t] > 0.5f) {
          id = tgt[(m0A + tid) * T_SZ + (t - 1)];
        } else {
          const u64* p = pk + (size_t)(m0A + tid) * 32;
          const unsigned tagw = (unsigned)((t - 1) & 0xFF);
          u64 best = 0ull;
#pragma unroll 1
          for (int q = 0; q < 32; ++q) {
            u64 v = aload64(p + q);
            while ((unsigned)(v & 0xFFu) != tagw) {
              __builtin_amdgcn_s_sleep(1);
              v = aload64(p + q);
            }
            best = (v > best) ? v : best;
          }
          id = 1023 - (int)((best >> 8) & 0x3FF);
        }
      }
      idx_s[tid] = id;
    }
    __syncthreads();

    {
      float acc[4][4];
#pragma unroll
      for (int i = 0; i < 4; ++i)
#pragma unroll
        for (int j = 0; j < 4; ++j) acc[i][j] = 0.f;

      float4 ra[2], rb[2];
      auto loadA = [&](int s, float4* r) {
        const int k = kbA + s * 16 + afA;
#pragma unroll
        for (int i = 0; i < 2; ++i) {
          const int m_ = amA + i * 16;
          if (k < 512)
            r[i] = *(const float4*)(etbl + (size_t)idx_s[m_] * 512 + k);
          else
            r[i] = aload4(hRead + (size_t)(m0A + m_) * H_SZ + (k - 512));
        }
      };
      auto loadB = [&](int s, float4* r) {
#pragma unroll
        for (int i = 0; i < 2; ++i)
          r[i] = *(const float4*)(Wt + (size_t)(kbA + s * 16 + bkA + i * 8) * NG + colA);
      };

      loadA(0, ra); loadB(0, rb);
#pragma unroll 1
      for (int s = 0; s < 8; ++s) {
#pragma unroll
        for (int i = 0; i < 2; ++i) {
          const int m_ = amA + i * 16;
          As[(afA + 0) * 36 + m_] = ra[i].x;
          As[(afA + 1) * 36 + m_] = ra[i].y;
          As[(afA + 2) * 36 + m_] = ra[i].z;
          As[(afA + 3) * 36 + m_] = ra[i].w;
          *(float4*)(Bs + (bkA + i * 8) * 36 + bnA) = rb[i];
        }
        float4 na[2], nb[2];
        if (s < 7) { loadA(s + 1, na); loadB(s + 1, nb); }
#pragma unroll
        for (int k = 0; k < 16; ++k) {
          float4 a = *(const float4*)(As + k * 36 + rg * 4);
          float4 b = *(const float4*)(Bs + k * 36 + cg * 4);
          acc[0][0] = fmaf(a.x, b.x, acc[0][0]); acc[0][1] = fmaf(a.x, b.y, acc[0][1]);
          acc[0][2] = fmaf(a.x, b.z, acc[0][2]); acc[0][3] = fmaf(a.x, b.w, acc[0][3]);
          acc[1][0] = fmaf(a.y, b.x, acc[1][0]); acc[1][1] = fmaf(a.y, b.y, acc[1][1]);
          acc[1][2] = fmaf(a.y, b.z, acc[1][2]); acc[1][3] = fmaf(a.y, b.w, acc[1][3]);
          acc[2][0] = fmaf(a.z, b.x, acc[2][0]); acc[2][1] = fmaf(a.z, b.y, acc[2][1]);
          acc[2][2] = fmaf(a.z, b.z, acc[2][2]); acc[2][3] = fmaf(a.z, b.w, acc[2][3]);
          acc[3][0] = fmaf(a.w, b.x, acc[3][0]); acc[3][1] = fmaf(a.w, b.y, acc[3][1]);
          acc[3][2] = fmaf(a.w, b.z, acc[3][2]); acc[3][3] = fmaf(a.w, b.w, acc[3][3]);
        }
        if (s < 7) { ra[0] = na[0]; ra[1] = na[1]; rb[0] = nb[0]; rb[1] = nb[1]; }
      }
      __syncthreads();
#pragma unroll
      for (int i = 0; i < 4; ++i)
#pragma unroll
        for (int j = 0; j < 4; ++j)
          smem[w * 1024 + (rg * 4 + i) * 32 + cg * 4 + j] = acc[i][j];
      __syncthreads();

      if (tid < 256) {
        float gv[4];
#pragma unroll
        for (int g = 0; g < 4; ++g) {
          float s_ = bsr[g];
          const int j = g * 8 + qlc;
#pragma unroll
          for (int w2 = 0; w2 < 8; ++w2) s_ += smem[w2 * 1024 + mlc * 32 + j];
          gv[g] = s_;
        }
        const float cn = sigf(gv[1]) * creg + sigf(gv[0]) * tanhf(gv[2]);
        creg = cn;
        astore(hWrite + hIdx, sigf(gv[3]) * tanhf(cn));
      }
    }
    bcast_barrier(arrive, (unsigned)(t + 1));

    // ---------------- phase B: logits + tagged argmax partials ----------------
    {
      float acc[2][4];
#pragma unroll
      for (int i = 0; i < 2; ++i)
#pragma unroll
        for (int j = 0; j < 4; ++j) acc[i][j] = 0.f;

      float4 ra; float4 rb[2];
      auto loadA2 = [&](int s, float4& r) {
        r = aload4(hWrite + (size_t)(m0B + amB) * H_SZ + kbB + s * 16 + afA);
      };
      auto loadB2 = [&](int s, float4* r) {
#pragma unroll
        for (int i = 0; i < 2; ++i)
          r[i] = *(const float4*)(WoT + (size_t)(kbB + s * 16 + bkA + i * 8) * VP + n0B + bnA);
      };

      loadA2(0, ra); loadB2(0, rb);
#pragma unroll 1
      for (int s = 0; s < 4; ++s) {
        As2[(afA + 0) * 20 + amB] = ra.x;
        As2[(afA + 1) * 20 + amB] = ra.y;
        As2[(afA + 2) * 20 + amB] = ra.z;
        As2[(afA + 3) * 20 + amB] = ra.w;
#pragma unroll
        for (int i = 0; i < 2; ++i) *(float4*)(Bs2 + (bkA + i * 8) * 36 + bnA) = rb[i];
        float4 na; float4 nb[2];
        if (s < 3) { loadA2(s + 1, na); loadB2(s + 1, nb); }
#pragma unroll
        for (int k = 0; k < 16; ++k) {
          float2 a = *(const float2*)(As2 + k * 20 + rg * 2);
          float4 b = *(const float4*)(Bs2 + k * 36 + cg * 4);
          acc[0][0] = fmaf(a.x, b.x, acc[0][0]); acc[0][1] = fmaf(a.x, b.y, acc[0][1]);
          acc[0][2] = fmaf(a.x, b.z, acc[0][2]); acc[0][3] = fmaf(a.x, b.w, acc[0][3]);
          acc[1][0] = fmaf(a.y, b.x, acc[1][0]); acc[1][1] = fmaf(a.y, b.y, acc[1][1]);
          acc[1][2] = fmaf(a.y, b.z, acc[1][2]); acc[1][3] = fmaf(a.y, b.w, acc[1][3]);
        }
        if (s < 3) { ra = na; rb[0] = nb[0]; rb[1] = nb[1]; }
      }
      __syncthreads();
#pragma unroll
      for (int i = 0; i < 2; ++i)
#pragma unroll
        for (int j = 0; j < 4; ++j)
          smem[w * 512 + (rg * 2 + i) * 32 + cg * 4 + j] = acc[i][j];
      __syncthreads();

      float sres = bor;
#pragma unroll
      for (int w2 = 0; w2 < 8; ++w2) sres += smem[w2 * 512 + tid];
      u64 p = 0ull;
      if (ngB < V_SZ) {
        out[outBase + (size_t)t * V_SZ] = sres;
        // [key:32][1023-ng:10]<<8 | [t&0xFF]: tag equal within step -> tie-neutral
        p = ((u64)fkey(sres) << 32) | ((u64)(unsigned)(1023 - ngB) << 8)
            | (u64)(unsigned)(t & 0xFF);
      }
#pragma unroll
      for (int d = 16; d >= 1; d >>= 1) {
        u64 o = __shfl_xor(p, d, 64);
        p = (o > p) ? o : p;
      }
      if (nlb == 0) astore64(pk + (size_t)mgB * 32 + vt, p);
    }
    // no post-B barrier: pk RAW handled by tag spin, WAR by next mid-step barrier
  }

  // ---------------- final h, c tail ----------------
  const size_t off = (size_t)B_SZ * T_SZ * V_SZ;
  if (tid < 256) {
    out[off + (size_t)bid * 256 + tid] = aload(h0buf + (size_t)bid * 256 + tid);
    out[off + 65536 + hIdx] = creg;
  }
}

// ---------------- launcher ----------------
extern "C" void kernel_launch(void* const* d_in, const int* in_sizes, int n_in,
                              void* d_out, int out_size, void* d_ws, size_t ws_size,
                              hipStream_t stream) {
  (void)in_sizes; (void)n_in; (void)out_size; (void)ws_size;
  const float* ctx   = (const float*)d_in[0];
  const int*   tgt   = (const int*)d_in[1];
  const float* coin  = (const float*)d_in[2];
  const float* etbl  = (const float*)d_in[3];
  const float* W_ih  = (const float*)d_in[4];
  const float* W_hh  = (const float*)d_in[5];
  const float* b_ih  = (const float*)d_in[6];
  const float* b_hh  = (const float*)d_in[7];
  const float* W_out = (const float*)d_in[8];
  const float* b_out = (const float*)d_in[9];
  float* out = (float*)d_out;

  float* ws    = (float*)d_ws;
  float* Wt    = ws;                       // 1024*2048
  float* Wtc   = Wt + 2097152;             // 512*2048
  float* WoT   = Wtc + 1048576;            // 512*1024 (zero-padded cols >= 1000)
  float* base  = WoT + 524288;             // 128*2048
  float* h0    = base + 262144;            // 128*512
  float* h1    = h0 + 65536;               // 128*512
  u64*   pk    = (u64*)(h1 + 65536);       // 128*32 tagged argmax partials
  float* bo    = (float*)(pk + 4096);      // 1024 padded b_out
  unsigned* arrive = (unsigned*)(bo + 1024); // 512 words: flags[0..255], go @320

  hipLaunchKernelGGL(k_transpose, dim3(64, 16), dim3(256), 0, stream,
                     W_ih, 1024, 512, Wt, NG, 2048);
  hipLaunchKernelGGL(k_transpose, dim3(64, 16), dim3(256), 0, stream,
                     W_hh, 512, 0, Wt + (size_t)512 * NG, NG, 2048);
  hipLaunchKernelGGL(k_transpose, dim3(64, 16), dim3(256), 0, stream,
                     W_ih, 1024, 0, Wtc, NG, 2048);
  hipLaunchKernelGGL(k_transpose, dim3(32, 16), dim3(256), 0, stream,
                     W_out, 512, 0, WoT, VP, 1000);
  hipLaunchKernelGGL(k_base, dim3(64, 4), dim3(256), 0, stream, ctx, Wtc, b_ih, b_hh, base);
  hipLaunchKernelGGL(k_init, dim3(256), dim3(256), 0, stream, ctx, b_out, h0, bo, arrive);

  void* args[] = { (void*)&Wt, (void*)&WoT, (void*)&base, (void*)&etbl, (void*)&coin,
                   (void*)&tgt, (void*)&bo, (void*)&h0, (void*)&h1, (void*)&out,
                   (void*)&pk, (void*)&arrive };
  hipLaunchCooperativeKernel((void*)k_persist, dim3(256), dim3(512), args, 0, stream);
}